// Round 14
// baseline (1447.833 us; speedup 1.0000x reference)
//
#include <hip/hip_runtime.h>
#include <math.h>

// GlimpseDecoder: B=512, N=T=200, D=128, H=8, dk=16
// R13 = R12 structure + AGPR pinning ("+a" inline-asm) on all persistent
// operands (gk/lr/vr/cb). Evidence R5-R12: allocator caps ~128 arch VGPRs and
// rematerializes readonly global loads each step (hidden L2/L3 reload stalls
// on every compat/glimpse/logit chain). gfx950 unified RF: the AGPR half is
// unused here -> pin persistents there, remat impossible (asm is opaque).

#define Bsz 512
#define Nn  200
#define Dd  128
#define TANH_CLIP 10.0f
#define NEG_INF  -1e9f
#define LOG2E 1.4426950408889634f
#define LN2   0.6931471805599453f
#define QSCALE (0.25f * LOG2E)                       // 1/sqrt(16) * log2(e)
#define LSCALE (0.08838834764831845f * 2.0f * LOG2E) // 1/sqrt(128)*2*log2(e)

typedef float v2f __attribute__((ext_vector_type(2)));

__device__ __forceinline__ v2f pkfma(v2f a, v2f b, v2f c) {
    return __builtin_elementwise_fma(a, b, c);
}
__device__ __forceinline__ float fast_rcp(float x) { return __builtin_amdgcn_rcpf(x); }
__device__ __forceinline__ float rdlane(float v, int l) {
    union { float f; int i; } u; u.f = v;
    u.i = __builtin_amdgcn_readlane(u.i, l);
    return u.f;
}
// Pin a value into an ACCUMULATION register (AGPR). Opaque to the optimizer:
// no rematerialization from global possible; AGPR file has zero pressure.
#define PINA(x)  asm volatile("" : "+a"(x))
#define PINA4(v) do { PINA((v).x); PINA((v).y); PINA((v).z); PINA((v).w); } while (0)

// ---- DPP helpers (VALU cross-lane; no LDS pipe) ----
template <int CTRL, int RMASK, bool BC>
__device__ __forceinline__ float dppf(float x, float oldv) {
    int r = __builtin_amdgcn_update_dpp(__builtin_bit_cast(int, oldv),
                                        __builtin_bit_cast(int, x),
                                        CTRL, RMASK, 0xf, BC);
    return __builtin_bit_cast(float, r);
}
template <int CTRL, int RMASK, bool BC>
__device__ __forceinline__ int dppi(int x, int oldv) {
    return __builtin_amdgcn_update_dpp(oldv, x, CTRL, RMASK, 0xf, BC);
}
__device__ __forceinline__ float wave_sum63(float x) {
    x += dppf<0x111, 0xf, true >(x, 0.f);
    x += dppf<0x112, 0xf, true >(x, 0.f);
    x += dppf<0x114, 0xf, true >(x, 0.f);
    x += dppf<0x118, 0xf, true >(x, 0.f);
    x += dppf<0x142, 0xa, false>(x, 0.f);
    x += dppf<0x143, 0xc, false>(x, 0.f);
    return x;
}
__device__ __forceinline__ float wave_max63(float x) {
    x = fmaxf(x, dppf<0x111, 0xf, false>(x, -INFINITY));
    x = fmaxf(x, dppf<0x112, 0xf, false>(x, -INFINITY));
    x = fmaxf(x, dppf<0x114, 0xf, false>(x, -INFINITY));
    x = fmaxf(x, dppf<0x118, 0xf, false>(x, -INFINITY));
    x = fmaxf(x, dppf<0x142, 0xa, false>(x, -INFINITY));
    x = fmaxf(x, dppf<0x143, 0xc, false>(x, -INFINITY));
    return x;
}

__device__ __forceinline__ float dot16pk(const float4* g4, const float4* q4) {
    const v2f* g = (const v2f*)g4;
    const v2f* q = (const v2f*)q4;
    v2f a0 = g[0] * q[0];
    v2f a1 = g[1] * q[1];
    a0 = pkfma(g[2], q[2], a0);
    a1 = pkfma(g[3], q[3], a1);
    a0 = pkfma(g[4], q[4], a0);
    a1 = pkfma(g[5], q[5], a1);
    a0 = pkfma(g[6], q[6], a0);
    a1 = pkfma(g[7], q[7], a1);
    const v2f a = a0 + a1;
    return a.x + a.y;
}

// ---------------- Kernel A: tiled proj = emb @ W_node -> gk*QS, gv, lk*LS ----
__global__ __launch_bounds__(256, 3) void proj_kernel(
    const float* __restrict__ emb, const float* __restrict__ Wn,
    float* __restrict__ gk, float* __restrict__ gv, float* __restrict__ lk)
{
    const int bid = blockIdx.x;
    const int cg  = bid % 3;
    const int rowBase = (bid / 3) * 64;
    const int t  = threadIdx.x;
    const int c4 = t & 31;
    const int r8 = t >> 5;

    __shared__ __align__(16) float wn_s[64][128];
    __shared__ __align__(16) float e_s[64][68];

    float acc[8][4];
#pragma unroll
    for (int j = 0; j < 8; ++j)
#pragma unroll
        for (int m = 0; m < 4; ++m) acc[j][m] = 0.f;

    for (int kh = 0; kh < 2; ++kh) {
#pragma unroll
        for (int i = 0; i < 8; ++i) {
            const int idx = t + 256 * i;
            const int kr = idx >> 5, cc = (idx & 31) * 4;
            *(float4*)&wn_s[kr][cc] =
                *(const float4*)&Wn[(size_t)(kh * 64 + kr) * 384 + 128 * cg + cc];
        }
#pragma unroll
        for (int i = 0; i < 4; ++i) {
            const int idx = t + 256 * i;
            const int rr = idx >> 4, kk4 = (idx & 15) * 4;
            *(float4*)&e_s[rr][kk4] =
                *(const float4*)&emb[(size_t)(rowBase + rr) * Dd + kh * 64 + kk4];
        }
        __syncthreads();

#pragma unroll
        for (int k4 = 0; k4 < 16; ++k4) {
            float4 er[8];
#pragma unroll
            for (int j = 0; j < 8; ++j)
                er[j] = *(const float4*)&e_s[8 * r8 + j][4 * k4];
#pragma unroll
            for (int m = 0; m < 4; ++m) {
                const float4 wv = *(const float4*)&wn_s[4 * k4 + m][4 * c4];
#pragma unroll
                for (int j = 0; j < 8; ++j) {
                    const float ev = (m == 0) ? er[j].x : (m == 1) ? er[j].y
                                   : (m == 2) ? er[j].z : er[j].w;
                    acc[j][0] = fmaf(ev, wv.x, acc[j][0]);
                    acc[j][1] = fmaf(ev, wv.y, acc[j][1]);
                    acc[j][2] = fmaf(ev, wv.z, acc[j][2]);
                    acc[j][3] = fmaf(ev, wv.w, acc[j][3]);
                }
            }
        }
        __syncthreads();
    }

    float* out = (cg == 0) ? gk : (cg == 1) ? gv : lk;
    const float scl = (cg == 0) ? QSCALE : (cg == 2) ? LSCALE : 1.0f;
#pragma unroll
    for (int j = 0; j < 8; ++j) {
        float4 v;
        v.x = acc[j][0] * scl; v.y = acc[j][1] * scl;
        v.z = acc[j][2] * scl; v.w = acc[j][3] * scl;
        *(float4*)&out[(size_t)(rowBase + 8 * r8 + j) * Dd + 4 * c4] = v;
    }
}

// ---------------- Kernel B: greedy decode -------------------------------------
__global__ __launch_bounds__(512, 2) void decode_kernel(
    const float* __restrict__ emb,
    const float* __restrict__ Wf,   // W_fixed [D][D]
    const float* __restrict__ Wsp,  // W_step  [D][D]
    const float* __restrict__ gk, const float* __restrict__ gv,
    const float* __restrict__ lk,
    float* __restrict__ out_logp,   // [B][T][N]
    float* __restrict__ out_pi)     // [B][T] (as float)
{
    const int b    = blockIdx.x;
    const int t    = threadIdx.x;
    const int lane = t & 63;
    const int w    = t >> 6;      // wave id == head
    const int g    = t >> 7;      // prologue group 0..3
    const int d    = t & 127;     // prologue col

    __shared__ __align__(16) float qall_s[201 * Dd];   // 100.5 KB raw q-base
    __shared__ __align__(16) float wchunk_s[16][Dd];   // 8 KB
    __shared__ __align__(16) float red[4][Dd];         // 2 KB
    __shared__ __align__(16) float ctx0_s[Dd];
    __shared__ __align__(16) float fixedc_s[Dd];       // RAW
    __shared__             float smp[256 * 9];         // 9 KB logit partials
    __shared__ __align__(16) float4 cand[8];           // per-wave candidates

    const float* embB = emb + (size_t)b * Nn * Dd;
    const float* gkB  = gk  + (size_t)b * Nn * Dd;
    const float* gvB  = gv  + (size_t)b * Nn * Dd;
    const float* lkB  = lk  + (size_t)b * Nn * Dd;

    // ================= prologue (verified R7/R8/R12) =================
    {
        const float4* e4  = (const float4*)embB;
        float4*       es4 = (float4*)qall_s;
#pragma unroll
        for (int it = 0; it < 12; ++it) es4[t + 512 * it] = e4[t + 512 * it];
        if (t < 256) es4[t + 6144] = e4[t + 6144];
    }
    __syncthreads();
    {
        float s = 0.f;
#pragma unroll
        for (int k = 0; k < 50; ++k) s += qall_s[(50 * g + k) * Dd + d];
        red[g][d] = s;
    }
    __syncthreads();
    if (t < 128) ctx0_s[t] = (red[0][t] + red[1][t] + red[2][t] + red[3][t]) * (1.0f / 200.0f);
    __syncthreads();
    {
        float s = 0.f;
#pragma unroll
        for (int j = 0; j < 32; ++j)
            s = fmaf(ctx0_s[32 * g + j], Wf[(32 * g + j) * Dd + d], s);
        red[g][d] = s;
    }
    __syncthreads();
    if (t < 128) {
        fixedc_s[t] = red[0][t] + red[1][t] + red[2][t] + red[3][t];
        qall_s[200 * Dd + t] = ctx0_s[t];
    }
    __syncthreads();

    float qr[52];
#pragma unroll
    for (int i = 0; i < 52; ++i) qr[i] = 0.f;
    for (int kc = 0; kc < 8; ++kc) {
        {
            const int kr = t >> 5, cc = (t & 31) * 4;
            *(float4*)&wchunk_s[kr][cc] =
                *(const float4*)&Wsp[(size_t)(16 * kc + kr) * Dd + cc];
        }
        __syncthreads();
#pragma unroll
        for (int i = 0; i < 52; ++i) {
            const int r = 52 * g + i;
            if (r < 201) {
#pragma unroll
                for (int j4 = 0; j4 < 4; ++j4) {
                    const float4 ev = *(const float4*)&qall_s[r * Dd + 16 * kc + 4 * j4];
                    qr[i] = fmaf(ev.x, wchunk_s[4 * j4 + 0][d], qr[i]);
                    qr[i] = fmaf(ev.y, wchunk_s[4 * j4 + 1][d], qr[i]);
                    qr[i] = fmaf(ev.z, wchunk_s[4 * j4 + 2][d], qr[i]);
                    qr[i] = fmaf(ev.w, wchunk_s[4 * j4 + 3][d], qr[i]);
                }
            }
        }
        __syncthreads();
    }
#pragma unroll
    for (int i = 0; i < 52; ++i) {
        const int r = 52 * g + i;
        if (r < 201) qall_s[r * Dd + d] = qr[i];
    }
    __syncthreads();

    // ---------------- persistent registers (pinned into AGPRs) ----------------
    float4 gk0[4], gk1[4], gk2[4], gk3[4];  // prescaled K frags: n = lane+64k
    float4 lr[4][4];                        // prescaled logit-K, n = lane+64k
    float4 vr[4][4];                        // V rows n = lane+64k, cols 16w..
    float  cb[4];                           // compat bias: gk_pre . fixedc
    {
        const int n3 = (lane < 8) ? lane + 192 : 199;
        const float4* s0 = (const float4*)(gkB + (size_t)(lane      ) * Dd + 16 * w);
        const float4* s1 = (const float4*)(gkB + (size_t)(lane +  64) * Dd + 16 * w);
        const float4* s2 = (const float4*)(gkB + (size_t)(lane + 128) * Dd + 16 * w);
        const float4* s3 = (const float4*)(gkB + (size_t)n3 * Dd + 16 * w);
#pragma unroll
        for (int i = 0; i < 4; ++i) { gk0[i]=s0[i]; gk1[i]=s1[i]; gk2[i]=s2[i]; gk3[i]=s3[i]; }
        const float4* l0 = (const float4*)(lkB + (size_t)(lane      ) * Dd + 16 * w);
        const float4* l1 = (const float4*)(lkB + (size_t)(lane +  64) * Dd + 16 * w);
        const float4* l2 = (const float4*)(lkB + (size_t)(lane + 128) * Dd + 16 * w);
        const float4* l3 = (const float4*)(lkB + (size_t)n3 * Dd + 16 * w);
#pragma unroll
        for (int i = 0; i < 4; ++i) { lr[0][i]=l0[i]; lr[1][i]=l1[i]; lr[2][i]=l2[i]; lr[3][i]=l3[i]; }
        const float4* v0 = (const float4*)(gvB + (size_t)(lane      ) * Dd + 16 * w);
        const float4* v1 = (const float4*)(gvB + (size_t)(lane +  64) * Dd + 16 * w);
        const float4* v2 = (const float4*)(gvB + (size_t)(lane + 128) * Dd + 16 * w);
        const float4* v3 = (const float4*)(gvB + (size_t)n3 * Dd + 16 * w);
#pragma unroll
        for (int i = 0; i < 4; ++i) { vr[0][i]=v0[i]; vr[1][i]=v1[i]; vr[2][i]=v2[i]; vr[3][i]=v3[i]; }
    }
    // Pin into AGPRs: no remat, no arch-VGPR pressure (unified RF, AGPR half idle)
#pragma unroll
    for (int i = 0; i < 4; ++i) {
        PINA4(gk0[i]); PINA4(gk1[i]); PINA4(gk2[i]); PINA4(gk3[i]);
        PINA4(lr[0][i]); PINA4(lr[1][i]); PINA4(lr[2][i]); PINA4(lr[3][i]);
        PINA4(vr[0][i]); PINA4(vr[1][i]); PINA4(vr[2][i]); PINA4(vr[3][i]);
    }
    {
        float4 fcf[4];
        const float4* fcp = (const float4*)(fixedc_s + 16 * w);
#pragma unroll
        for (int i = 0; i < 4; ++i) fcf[i] = fcp[i];
        cb[0] = dot16pk(gk0, fcf);
        cb[1] = dot16pk(gk1, fcf);
        cb[2] = dot16pk(gk2, fcf);
        cb[3] = dot16pk(gk3, fcf);
        PINA(cb[0]); PINA(cb[1]); PINA(cb[2]); PINA(cb[3]);
    }

    const int nB = 32 * w + (lane >> 1);    // finish-phase n owned by this lane
    const int hB = lane & 1;                // finish half

    // ================= decode loop =================
    unsigned int visA = 0;   // bits 0..3: visited(lane + 64k)
    unsigned int visB = 0;   // bit 0: visited(nB)
    int sel_prev = 200;      // row 200 = ctx0 q-base

    for (int step = 0; step < Nn; ++step) {
        // ---- A: q read (LDS broadcast) -> compat -> p ----
        float4 qv[4];
        {
            const float4* qp = (const float4*)(qall_s + sel_prev * Dd + 16 * w);
            qv[0] = qp[0]; qv[1] = qp[1]; qv[2] = qp[2]; qv[3] = qp[3];
        }
        float pk4[4];
        {
            float x0 = dot16pk(gk0, qv) + cb[0];
            float x1 = dot16pk(gk1, qv) + cb[1];
            float x2 = dot16pk(gk2, qv) + cb[2];
            float x3 = dot16pk(gk3, qv) + cb[3];
            x0 = (visA & 1u) ? -1e30f : x0;
            x1 = (visA & 2u) ? -1e30f : x1;
            x2 = (visA & 4u) ? -1e30f : x2;
            x3 = (lane < 8 && !(visA & 8u)) ? x3 : -1e30f;
            pk4[0] = exp2f(x0); pk4[1] = exp2f(x1);
            pk4[2] = exp2f(x2); pk4[3] = exp2f(x3);
        }
        // ---- glimpse: two 8-col passes, DPP reduce ----
        float sgl[16];
        float invps;
        {
            float pssum = wave_sum63((pk4[0] + pk4[1]) + (pk4[2] + pk4[3]));
#pragma unroll
            for (int half = 0; half < 2; ++half) {
                v2f gacc[4];
#pragma unroll
                for (int i = 0; i < 4; ++i) gacc[i] = (v2f){0.f, 0.f};
#pragma unroll
                for (int k = 0; k < 4; ++k) {
                    const v2f pp = (v2f){pk4[k], pk4[k]};
#pragma unroll
                    for (int i = 0; i < 2; ++i) {
                        const float4 v = vr[k][2 * half + i];
                        gacc[2*i+0] = pkfma((v2f){v.x, v.y}, pp, gacc[2*i+0]);
                        gacc[2*i+1] = pkfma((v2f){v.z, v.w}, pp, gacc[2*i+1]);
                    }
                }
#pragma unroll
                for (int i = 0; i < 4; ++i) {
                    float ra = wave_sum63(gacc[i].x);
                    float rb = wave_sum63(gacc[i].y);
                    sgl[8 * half + 2*i]     = rdlane(ra, 63);
                    sgl[8 * half + 2*i + 1] = rdlane(rb, 63);
                }
            }
            invps = fast_rcp(rdlane(pssum, 63));
        }
        // ---- partial logits (own head) for own 4 n's -> smp ----
        {
            float* sp = smp;
#pragma unroll
            for (int k = 0; k < 4; ++k) {
                float a = 0.f;
#pragma unroll
                for (int i = 0; i < 4; ++i) {
                    const float4 L = lr[k][i];
                    a = fmaf(L.x, sgl[4*i+0], a);
                    a = fmaf(L.y, sgl[4*i+1], a);
                    a = fmaf(L.z, sgl[4*i+2], a);
                    a = fmaf(L.w, sgl[4*i+3], a);
                }
                a *= invps;
                if (k < 3)          sp[(lane + 64*k) * 9 + w] = a;
                else if (lane < 8)  sp[(lane + 192)  * 9 + w] = a;
            }
        }
        __syncthreads();                                   // bar1: smp ready

        // ---- B: finish own 32-n slice ----
        float lfin;
        {
            const int base = nB * 9 + 4 * hB;
            float s4 = (smp[base] + smp[base+1]) + (smp[base+2] + smp[base+3]);
            s4 += dppf<0xB1, 0xf, true>(s4, 0.f);          // pair-combine (xor1)
            const float u  = exp2f(s4);                     // e^{2x}, lk prescaled
            const float lv = TANH_CLIP - 2.0f * TANH_CLIP * fast_rcp(u + 1.0f);
            lfin = (nB >= Nn) ? -INFINITY : ((visB & 1u) ? NEG_INF : lv);
        }
        const float mx_s = rdlane(wave_max63(lfin), 63);
        const unsigned long long bal = __ballot(lfin == mx_s);
        const int sel_w = 32 * w + (__builtin_ctzll(bal) >> 1);
        float e = (hB == 0) ? exp2f((lfin - 10.f) * LOG2E) : 0.f;
        const float esum_w = wave_sum63(e);
        if (lane == 63) {
            float4 c;
            c.x = mx_s; c.y = __int_as_float(sel_w); c.z = esum_w; c.w = 0.f;
            cand[w] = c;
        }
        __syncthreads();                                   // bar2: cand ready

        // ---- final: 8-way candidate combine ----
        int sel; float lse;
        {
            const float4 c = cand[lane & 7];
            float cv = c.x; int ci = __float_as_int(c.y); float ce = c.z;
#define CSTEP(CTRL) { \
            float ov = dppf<CTRL, 0xf, true>(cv, 0.f); \
            int   oi = dppi<CTRL, 0xf, true>(ci, 0);   \
            float oe = dppf<CTRL, 0xf, true>(ce, 0.f); \
            ce += oe; \
            if (ov > cv || (ov == cv && oi < ci)) { cv = ov; ci = oi; } }
            CSTEP(0xB1)
            CSTEP(0x4E)
            CSTEP(0x141)
#undef CSTEP
            sel = ci;
            lse = log2f(ce) * LN2 + 10.f;
        }

        // ---- outputs + state ----
        if (hB == 0 && nB < Nn)
            out_logp[((size_t)b * Nn + step) * Nn + nB] = lfin - lse;
        if (t == 0) out_pi[(size_t)b * Nn + step] = (float)sel;

        visA |= (sel == lane)        ? 1u : 0u;
        visA |= (sel == lane + 64)   ? 2u : 0u;
        visA |= (sel == lane + 128)  ? 4u : 0u;
        visA |= (sel == lane + 192)  ? 8u : 0u;
        visB |= (sel == nB)          ? 1u : 0u;
        sel_prev = sel;
    }
}

// ----------------------------------------------------------------------------
extern "C" void kernel_launch(void* const* d_in, const int* in_sizes, int n_in,
                              void* d_out, int out_size, void* d_ws, size_t ws_size,
                              hipStream_t stream) {
    (void)in_sizes; (void)n_in; (void)out_size; (void)ws_size;
    const float* emb = (const float*)d_in[0];   // [B,N,D]
    const float* Wn  = (const float*)d_in[1];   // [D,3D]
    const float* Wf  = (const float*)d_in[2];   // [D,D]
    const float* Wsp = (const float*)d_in[3];   // [D,D]

    const size_t BND = (size_t)Bsz * Nn * Dd;
    float* gk = (float*)d_ws;                   // prescaled by QSCALE
    float* gv = gk + BND;
    float* lk = gv + BND;                       // prescaled by LSCALE

    float* out_logp = (float*)d_out;                       // [B,T,N]
    float* out_pi   = out_logp + (size_t)Bsz * Nn * Nn;    // [B,T] as float

    proj_kernel<<<(Bsz * Nn / 64) * 3, 256, 0, stream>>>(emb, Wn, gk, gv, lk);
    decode_kernel<<<Bsz, 512, 0, stream>>>(emb, Wf, Wsp, gk, gv, lk,
                                           out_logp, out_pi);
}

// Round 15
// 952.781 us; speedup vs baseline: 1.5196x; 1.5196x over previous
//
#include <hip/hip_runtime.h>
#include <math.h>

// GlimpseDecoder: B=512, N=T=200, D=128, H=8, dk=16
// R14 = R7 skeleton (best, 997us; LDS-transpose glimpse, wave-private phase A)
//  + b128 glimpse reads (26xb64 -> 13xb128)
//  + R8's dedup finish (smp partials -> own 32-n slice -> cand exchange),
//    removing logits_s round-trip + dual 12-bpermute argmax/lse chains
//  + raw v_exp_f32 / v_log_f32 via __builtin_amdgcn_{exp2f,logf}.
// Theory: R7 is LDS-issue-bound (~70 LDS inst/wave-step); this cuts to ~40.

#define Bsz 512
#define Nn  200
#define Dd  128
#define TANH_CLIP 10.0f
#define NEG_INF  -1e9f
#define LOG2E 1.4426950408889634f
#define LN2   0.6931471805599453f
#define QSCALE (0.25f * LOG2E)                       // 1/sqrt(16) * log2(e)
#define LSCALE (0.08838834764831845f * 2.0f * LOG2E) // 1/sqrt(128)*2*log2(e)

typedef float v2f __attribute__((ext_vector_type(2)));

__device__ __forceinline__ v2f pkfma(v2f a, v2f b, v2f c) {
    return __builtin_elementwise_fma(a, b, c);
}
__device__ __forceinline__ float fast_rcp(float x) { return __builtin_amdgcn_rcpf(x); }
__device__ __forceinline__ float fexp2(float x)    { return __builtin_amdgcn_exp2f(x); }
__device__ __forceinline__ float flog2(float x)    { return __builtin_amdgcn_logf(x); }
__device__ __forceinline__ float rdlane(float v, int l) {
    union { float f; int i; } u; u.f = v;
    u.i = __builtin_amdgcn_readlane(u.i, l);
    return u.f;
}

// ---- DPP helpers ----
template <int CTRL, int RMASK, bool BC>
__device__ __forceinline__ float dppf(float x, float oldv) {
    int r = __builtin_amdgcn_update_dpp(__builtin_bit_cast(int, oldv),
                                        __builtin_bit_cast(int, x),
                                        CTRL, RMASK, 0xf, BC);
    return __builtin_bit_cast(float, r);
}
template <int CTRL, int RMASK, bool BC>
__device__ __forceinline__ int dppi(int x, int oldv) {
    return __builtin_amdgcn_update_dpp(oldv, x, CTRL, RMASK, 0xf, BC);
}
__device__ __forceinline__ float wave_sum63(float x) {
    x += dppf<0x111, 0xf, true >(x, 0.f);
    x += dppf<0x112, 0xf, true >(x, 0.f);
    x += dppf<0x114, 0xf, true >(x, 0.f);
    x += dppf<0x118, 0xf, true >(x, 0.f);
    x += dppf<0x142, 0xa, false>(x, 0.f);
    x += dppf<0x143, 0xc, false>(x, 0.f);
    return x;
}
__device__ __forceinline__ float wave_max63(float x) {
    x = fmaxf(x, dppf<0x111, 0xf, false>(x, -INFINITY));
    x = fmaxf(x, dppf<0x112, 0xf, false>(x, -INFINITY));
    x = fmaxf(x, dppf<0x114, 0xf, false>(x, -INFINITY));
    x = fmaxf(x, dppf<0x118, 0xf, false>(x, -INFINITY));
    x = fmaxf(x, dppf<0x142, 0xa, false>(x, -INFINITY));
    x = fmaxf(x, dppf<0x143, 0xc, false>(x, -INFINITY));
    return x;
}

__device__ __forceinline__ float dot16pk(const float4* g4, const float4* q4) {
    const v2f* g = (const v2f*)g4;
    const v2f* q = (const v2f*)q4;
    v2f a0 = g[0] * q[0];
    v2f a1 = g[1] * q[1];
    a0 = pkfma(g[2], q[2], a0);
    a1 = pkfma(g[3], q[3], a1);
    a0 = pkfma(g[4], q[4], a0);
    a1 = pkfma(g[5], q[5], a1);
    a0 = pkfma(g[6], q[6], a0);
    a1 = pkfma(g[7], q[7], a1);
    const v2f a = a0 + a1;
    return a.x + a.y;
}

// ---------------- Kernel A: tiled proj = emb @ W_node -> gk*QS, gv, lk*LS ----
__global__ __launch_bounds__(256, 3) void proj_kernel(
    const float* __restrict__ emb, const float* __restrict__ Wn,
    float* __restrict__ gk, float* __restrict__ gv, float* __restrict__ lk)
{
    const int bid = blockIdx.x;
    const int cg  = bid % 3;
    const int rowBase = (bid / 3) * 64;
    const int t  = threadIdx.x;
    const int c4 = t & 31;
    const int r8 = t >> 5;

    __shared__ __align__(16) float wn_s[64][128];
    __shared__ __align__(16) float e_s[64][68];

    float acc[8][4];
#pragma unroll
    for (int j = 0; j < 8; ++j)
#pragma unroll
        for (int m = 0; m < 4; ++m) acc[j][m] = 0.f;

    for (int kh = 0; kh < 2; ++kh) {
#pragma unroll
        for (int i = 0; i < 8; ++i) {
            const int idx = t + 256 * i;
            const int kr = idx >> 5, cc = (idx & 31) * 4;
            *(float4*)&wn_s[kr][cc] =
                *(const float4*)&Wn[(size_t)(kh * 64 + kr) * 384 + 128 * cg + cc];
        }
#pragma unroll
        for (int i = 0; i < 4; ++i) {
            const int idx = t + 256 * i;
            const int rr = idx >> 4, kk4 = (idx & 15) * 4;
            *(float4*)&e_s[rr][kk4] =
                *(const float4*)&emb[(size_t)(rowBase + rr) * Dd + kh * 64 + kk4];
        }
        __syncthreads();

#pragma unroll
        for (int k4 = 0; k4 < 16; ++k4) {
            float4 er[8];
#pragma unroll
            for (int j = 0; j < 8; ++j)
                er[j] = *(const float4*)&e_s[8 * r8 + j][4 * k4];
#pragma unroll
            for (int m = 0; m < 4; ++m) {
                const float4 wv = *(const float4*)&wn_s[4 * k4 + m][4 * c4];
#pragma unroll
                for (int j = 0; j < 8; ++j) {
                    const float ev = (m == 0) ? er[j].x : (m == 1) ? er[j].y
                                   : (m == 2) ? er[j].z : er[j].w;
                    acc[j][0] = fmaf(ev, wv.x, acc[j][0]);
                    acc[j][1] = fmaf(ev, wv.y, acc[j][1]);
                    acc[j][2] = fmaf(ev, wv.z, acc[j][2]);
                    acc[j][3] = fmaf(ev, wv.w, acc[j][3]);
                }
            }
        }
        __syncthreads();
    }

    float* out = (cg == 0) ? gk : (cg == 1) ? gv : lk;
    const float scl = (cg == 0) ? QSCALE : (cg == 2) ? LSCALE : 1.0f;
#pragma unroll
    for (int j = 0; j < 8; ++j) {
        float4 v;
        v.x = acc[j][0] * scl; v.y = acc[j][1] * scl;
        v.z = acc[j][2] * scl; v.w = acc[j][3] * scl;
        *(float4*)&out[(size_t)(rowBase + 8 * r8 + j) * Dd + 4 * c4] = v;
    }
}

// ---------------- Kernel B: greedy decode -------------------------------------
__global__ __launch_bounds__(512, 2) void decode_kernel(
    const float* __restrict__ emb,
    const float* __restrict__ Wf,   // W_fixed [D][D]
    const float* __restrict__ Wsp,  // W_step  [D][D]
    const float* __restrict__ gk, const float* __restrict__ gv,
    const float* __restrict__ lk,
    float* __restrict__ out_logp,   // [B][T][N]
    float* __restrict__ out_pi)     // [B][T] (as float)
{
    const int b    = blockIdx.x;
    const int t    = threadIdx.x;
    const int lane = t & 63;
    const int w    = t >> 6;      // wave id == head
    const int g    = t >> 7;      // prologue group 0..3
    const int d    = t & 127;     // prologue col
    const int jq   = lane >> 2;   // col within head (0..15)
    const int kk   = lane & 3;    // quad slot: glimpse n-slice

    __shared__ __align__(16) float qall_s[201 * Dd];   // 100.5 KB raw q-base
    __shared__ __align__(16) float wchunk_s[16][Dd];   // 8 KB
    __shared__ __align__(16) float red[4][Dd];         // 2 KB
    __shared__ __align__(16) float ctx0_s[Dd];
    __shared__ __align__(16) float fixedc_s[Dd];       // RAW
    __shared__ __align__(16) float sm2[8][256];        // wave-private p
    __shared__ __align__(16) float glimbc[8][16];
    __shared__             float smp[256 * 9];         // 9 KB logit partials
    __shared__ __align__(16) float4 cand[8];

    const float* embB = emb + (size_t)b * Nn * Dd;
    const float* gkB  = gk  + (size_t)b * Nn * Dd;
    const float* gvB  = gv  + (size_t)b * Nn * Dd;
    const float* lkB  = lk  + (size_t)b * Nn * Dd;

    // ================= prologue (verified R7-R13) =================
    {
        const float4* e4  = (const float4*)embB;
        float4*       es4 = (float4*)qall_s;
#pragma unroll
        for (int it = 0; it < 12; ++it) es4[t + 512 * it] = e4[t + 512 * it];
        if (t < 256) es4[t + 6144] = e4[t + 6144];
    }
    __syncthreads();
    {
        float s = 0.f;
#pragma unroll
        for (int k = 0; k < 50; ++k) s += qall_s[(50 * g + k) * Dd + d];
        red[g][d] = s;
    }
    __syncthreads();
    if (t < 128) ctx0_s[t] = (red[0][t] + red[1][t] + red[2][t] + red[3][t]) * (1.0f / 200.0f);
    __syncthreads();
    {
        float s = 0.f;
#pragma unroll
        for (int j = 0; j < 32; ++j)
            s = fmaf(ctx0_s[32 * g + j], Wf[(32 * g + j) * Dd + d], s);
        red[g][d] = s;
    }
    __syncthreads();
    if (t < 128) {
        fixedc_s[t] = red[0][t] + red[1][t] + red[2][t] + red[3][t];
        qall_s[200 * Dd + t] = ctx0_s[t];
    }
    __syncthreads();

    float qr[52];
#pragma unroll
    for (int i = 0; i < 52; ++i) qr[i] = 0.f;
    for (int kc = 0; kc < 8; ++kc) {
        {
            const int kr = t >> 5, cc = (t & 31) * 4;
            *(float4*)&wchunk_s[kr][cc] =
                *(const float4*)&Wsp[(size_t)(16 * kc + kr) * Dd + cc];
        }
        __syncthreads();
#pragma unroll
        for (int i = 0; i < 52; ++i) {
            const int r = 52 * g + i;
            if (r < 201) {
#pragma unroll
                for (int j4 = 0; j4 < 4; ++j4) {
                    const float4 ev = *(const float4*)&qall_s[r * Dd + 16 * kc + 4 * j4];
                    qr[i] = fmaf(ev.x, wchunk_s[4 * j4 + 0][d], qr[i]);
                    qr[i] = fmaf(ev.y, wchunk_s[4 * j4 + 1][d], qr[i]);
                    qr[i] = fmaf(ev.z, wchunk_s[4 * j4 + 2][d], qr[i]);
                    qr[i] = fmaf(ev.w, wchunk_s[4 * j4 + 3][d], qr[i]);
                }
            }
        }
        __syncthreads();
    }
#pragma unroll
    for (int i = 0; i < 52; ++i) {
        const int r = 52 * g + i;
        if (r < 201) qall_s[r * Dd + d] = qr[i];
    }
    __syncthreads();

    // ---------------- persistent operands (remat regime accepted) ----------
    float4 gk0[4], gk1[4], gk2[4], gk3[4];  // prescaled K frags: n = lane+64k
    float4 lr[4][4];                        // prescaled logit-K, n = lane+64k
    float  gva[52];                         // V rows 52kk..+51 (clamp), col 16w+jq
    float  cb[4];
    {
        const int n3 = (lane < 8) ? lane + 192 : 199;
        const float4* s0 = (const float4*)(gkB + (size_t)(lane      ) * Dd + 16 * w);
        const float4* s1 = (const float4*)(gkB + (size_t)(lane +  64) * Dd + 16 * w);
        const float4* s2 = (const float4*)(gkB + (size_t)(lane + 128) * Dd + 16 * w);
        const float4* s3 = (const float4*)(gkB + (size_t)n3 * Dd + 16 * w);
#pragma unroll
        for (int i = 0; i < 4; ++i) { gk0[i]=s0[i]; gk1[i]=s1[i]; gk2[i]=s2[i]; gk3[i]=s3[i]; }
        const float4* l0 = (const float4*)(lkB + (size_t)(lane      ) * Dd + 16 * w);
        const float4* l1 = (const float4*)(lkB + (size_t)(lane +  64) * Dd + 16 * w);
        const float4* l2 = (const float4*)(lkB + (size_t)(lane + 128) * Dd + 16 * w);
        const float4* l3 = (const float4*)(lkB + (size_t)n3 * Dd + 16 * w);
#pragma unroll
        for (int i = 0; i < 4; ++i) { lr[0][i]=l0[i]; lr[1][i]=l1[i]; lr[2][i]=l2[i]; lr[3][i]=l3[i]; }
    }
#pragma unroll
    for (int k = 0; k < 52; ++k) {
        int r = 52 * kk + k; r = r < 200 ? r : 199;
        gva[k] = gvB[(size_t)r * Dd + 16 * w + jq];
    }
    {
        float4 fcf[4];
        const float4* fcp = (const float4*)(fixedc_s + 16 * w);
#pragma unroll
        for (int i = 0; i < 4; ++i) fcf[i] = fcp[i];
        cb[0] = dot16pk(gk0, fcf);
        cb[1] = dot16pk(gk1, fcf);
        cb[2] = dot16pk(gk2, fcf);
        cb[3] = dot16pk(gk3, fcf);
    }

    const int nB = 32 * w + (lane >> 1);    // finish-phase n owned by this lane
    const int hB = lane & 1;                // finish half

    // ================= decode loop: 2 barriers/step =================
    unsigned int visA = 0;   // bits 0..3: visited(lane + 64k)
    unsigned int visB = 0;   // bit 0: visited(nB)
    int sel_prev = 200;      // row 200 = ctx0 q-base

    for (int step = 0; step < Nn; ++step) {
        // ---- phase A (wave-private) ----
        float4 qv[4];
        {
            const float4* qp = (const float4*)(qall_s + sel_prev * Dd + 16 * w);
            qv[0] = qp[0]; qv[1] = qp[1]; qv[2] = qp[2]; qv[3] = qp[3];
        }
        // compat -> p (log2 domain, prescaled)
        float p0, p1, p2, p3;
        {
            float x0 = dot16pk(gk0, qv) + cb[0];
            float x1 = dot16pk(gk1, qv) + cb[1];
            float x2 = dot16pk(gk2, qv) + cb[2];
            float x3 = dot16pk(gk3, qv) + cb[3];
            x0 = (visA & 1u) ? -1e30f : x0;
            x1 = (visA & 2u) ? -1e30f : x1;
            x2 = (visA & 4u) ? -1e30f : x2;
            x3 = (lane < 8 && !(visA & 8u)) ? x3 : -1e30f;
            p0 = fexp2(x0); p1 = fexp2(x1); p2 = fexp2(x2); p3 = fexp2(x3);
        }
        {
            float* prow = &sm2[w][0];
            prow[lane      ] = p0;
            prow[lane +  64] = p1;
            prow[lane + 128] = p2;
            prow[lane + 192] = p3;   // n in [200,256): zeros (masked lanes)
        }
        float ps = (p0 + p1) + (p2 + p3);
#pragma unroll
        for (int off = 1; off < 64; off <<= 1) ps += __shfl_xor(ps, off);
        const float invps = fast_rcp(ps);

        // glimpse (wave-private, LDS transpose, b128 reads)
        {
            const float4* a4  = (const float4*)(&sm2[w][52 * kk]);  // 208B -> 16B aligned
            float s0 = 0.f, s1 = 0.f, s2 = 0.f, s3 = 0.f;
#pragma unroll
            for (int k4 = 0; k4 < 13; ++k4) {
                const float4 av = a4[k4];
                s0 = fmaf(av.x, gva[4 * k4 + 0], s0);
                s1 = fmaf(av.y, gva[4 * k4 + 1], s1);
                s2 = fmaf(av.z, gva[4 * k4 + 2], s2);
                s3 = fmaf(av.w, gva[4 * k4 + 3], s3);
            }
            float gsum = (s0 + s1) + (s2 + s3);
            gsum += __shfl_xor(gsum, 1);
            gsum += __shfl_xor(gsum, 2);
            if (kk == 0) glimbc[w][jq] = gsum * invps;
        }
        float4 gw[4];
        {
            const float4* gbp = (const float4*)&glimbc[w][0];
            gw[0] = gbp[0]; gw[1] = gbp[1]; gw[2] = gbp[2]; gw[3] = gbp[3];
        }
        // partial logits (own head) for own 4 n's -> smp
        {
            const float a0 = dot16pk(lr[0], gw);
            const float a1 = dot16pk(lr[1], gw);
            const float a2 = dot16pk(lr[2], gw);
            const float a3 = dot16pk(lr[3], gw);
            smp[(lane      ) * 9 + w] = a0;
            smp[(lane +  64) * 9 + w] = a1;
            smp[(lane + 128) * 9 + w] = a2;
            if (lane < 8) smp[(lane + 192) * 9 + w] = a3;
        }
        __syncthreads();                                   // bar1: smp ready

        // ---- phase B: finish own 32-n slice ----
        float lfin;
        {
            const int base = nB * 9 + 4 * hB;
            float s4 = (smp[base] + smp[base+1]) + (smp[base+2] + smp[base+3]);
            s4 += dppf<0xB1, 0xf, true>(s4, 0.f);          // pair-combine (xor1)
            const float u  = fexp2(s4);                     // e^{2x}, lk prescaled
            const float lv = TANH_CLIP - 2.0f * TANH_CLIP * fast_rcp(u + 1.0f);
            lfin = (nB >= Nn) ? -INFINITY : ((visB & 1u) ? NEG_INF : lv);
        }
        const float mx_s = rdlane(wave_max63(lfin), 63);
        const unsigned long long bal = __ballot(lfin == mx_s);
        const int sel_w = 32 * w + (__builtin_ctzll(bal) >> 1);
        float e = (hB == 0) ? fexp2((lfin - 10.f) * LOG2E) : 0.f;
        const float esum_w = wave_sum63(e);
        if (lane == 63) {
            float4 c;
            c.x = mx_s; c.y = __int_as_float(sel_w); c.z = esum_w; c.w = 0.f;
            cand[w] = c;
        }
        __syncthreads();                                   // bar2: cand ready

        // ---- phase C: 8-way candidate combine ----
        int sel; float lse;
        {
            const float4 c = cand[lane & 7];
            float cv = c.x; int ci = __float_as_int(c.y); float ce = c.z;
#define CSTEP(CTRL) { \
            float ov = dppf<CTRL, 0xf, true>(cv, 0.f); \
            int   oi = dppi<CTRL, 0xf, true>(ci, 0);   \
            float oe = dppf<CTRL, 0xf, true>(ce, 0.f); \
            ce += oe; \
            if (ov > cv || (ov == cv && oi < ci)) { cv = ov; ci = oi; } }
            CSTEP(0xB1)
            CSTEP(0x4E)
            CSTEP(0x141)
#undef CSTEP
            sel = ci;
            lse = flog2(ce) * LN2 + 10.f;
        }

        // ---- outputs + state ----
        if (hB == 0 && nB < Nn)
            out_logp[((size_t)b * Nn + step) * Nn + nB] = lfin - lse;
        if (t == 0) out_pi[(size_t)b * Nn + step] = (float)sel;

        visA |= (sel == lane)        ? 1u : 0u;
        visA |= (sel == lane + 64)   ? 2u : 0u;
        visA |= (sel == lane + 128)  ? 4u : 0u;
        visA |= (sel == lane + 192)  ? 8u : 0u;
        visB |= (sel == nB)          ? 1u : 0u;
        sel_prev = sel;
    }
}

// ----------------------------------------------------------------------------
extern "C" void kernel_launch(void* const* d_in, const int* in_sizes, int n_in,
                              void* d_out, int out_size, void* d_ws, size_t ws_size,
                              hipStream_t stream) {
    (void)in_sizes; (void)n_in; (void)out_size; (void)ws_size;
    const float* emb = (const float*)d_in[0];   // [B,N,D]
    const float* Wn  = (const float*)d_in[1];   // [D,3D]
    const float* Wf  = (const float*)d_in[2];   // [D,D]
    const float* Wsp = (const float*)d_in[3];   // [D,D]

    const size_t BND = (size_t)Bsz * Nn * Dd;
    float* gk = (float*)d_ws;                   // prescaled by QSCALE
    float* gv = gk + BND;
    float* lk = gv + BND;                       // prescaled by LSCALE

    float* out_logp = (float*)d_out;                       // [B,T,N]
    float* out_pi   = out_logp + (size_t)Bsz * Nn * Nn;    // [B,T] as float

    proj_kernel<<<(Bsz * Nn / 64) * 3, 256, 0, stream>>>(emb, Wn, gk, gv, lk);
    decode_kernel<<<Bsz, 512, 0, stream>>>(emb, Wf, Wsp, gk, gv, lk,
                                           out_logp, out_pi);
}